// Round 2
// baseline (1159.074 us; speedup 1.0000x reference)
//
#include <hip/hip_runtime.h>
#include <cstdint>
#include <cstddef>

typedef __bf16 bf16;
typedef bf16  bf16x8 __attribute__((ext_vector_type(8)));
typedef bf16  bf16x4 __attribute__((ext_vector_type(4)));
typedef float f32x4  __attribute__((ext_vector_type(4)));

#define B_ 2
#define S_ 2048
#define D_ 1024
#define H_ 16
#define F_ 4096
#define E_ 8
#define T_ (B_*S_)   // 4096 tokens

// ---------------- async global->LDS, 16B per lane (dest = wave-uniform base + lane*16)
__device__ __forceinline__ void gl16(const bf16* g, bf16* l) {
    __builtin_amdgcn_global_load_lds(
        (const __attribute__((address_space(1))) void*)g,
        (__attribute__((address_space(3))) void*)l, 16, 0, 0);
}

// ---------------- transpose + fp32->bf16 convert:  in [R][C] f32  ->  out [C][R] bf16
__global__ __launch_bounds__(256) void transpose_convert(const float* __restrict__ in,
                                                         bf16* __restrict__ out,
                                                         int R, int C) {
    __shared__ float tile[32][33];
    size_t mat = blockIdx.z;
    in  += mat * (size_t)R * C;
    out += mat * (size_t)R * C;
    int c0 = blockIdx.x * 32, r0 = blockIdx.y * 32;
    for (int i = threadIdx.y; i < 32; i += 8)
        tile[i][threadIdx.x] = in[(size_t)(r0 + i) * C + c0 + threadIdx.x];
    __syncthreads();
    for (int i = threadIdx.y; i < 32; i += 8)
        out[(size_t)(c0 + i) * R + r0 + threadIdx.x] = (bf16)tile[threadIdx.x][i];
}

// ---------------- LayerNorm (eps=1e-5): writes bf16 (GEMM input) and optional fp32
__global__ __launch_bounds__(256) void ln_kernel(const float* __restrict__ xin,
                                                 const float* __restrict__ gam,
                                                 const float* __restrict__ bet,
                                                 bf16* __restrict__ obf,
                                                 float* __restrict__ of32) {
    int row = blockIdx.x, tid = threadIdx.x;
    const float4* xr = (const float4*)(xin + (size_t)row * D_);
    float4 v = xr[tid];
    float s  = v.x + v.y + v.z + v.w;
    float s2 = v.x*v.x + v.y*v.y + v.z*v.z + v.w*v.w;
    #pragma unroll
    for (int o = 1; o < 64; o <<= 1) { s += __shfl_xor(s, o); s2 += __shfl_xor(s2, o); }
    __shared__ float red[8];
    int wave = tid >> 6, lane = tid & 63;
    if (lane == 0) { red[wave] = s; red[4 + wave] = s2; }
    __syncthreads();
    s  = red[0] + red[1] + red[2] + red[3];
    s2 = red[4] + red[5] + red[6] + red[7];
    float m   = s * (1.0f / D_);
    float var = s2 * (1.0f / D_) - m * m;
    float rs  = rsqrtf(var + 1e-5f);
    float4 gv = ((const float4*)gam)[tid];
    float4 bv = ((const float4*)bet)[tid];
    float y0 = (v.x - m) * rs * gv.x + bv.x;
    float y1 = (v.y - m) * rs * gv.y + bv.y;
    float y2 = (v.z - m) * rs * gv.z + bv.z;
    float y3 = (v.w - m) * rs * gv.w + bv.w;
    bf16x4 ov; ov[0] = (bf16)y0; ov[1] = (bf16)y1; ov[2] = (bf16)y2; ov[3] = (bf16)y3;
    *(bf16x4*)(obf + (size_t)row * D_ + tid * 4) = ov;
    if (of32) {
        float4 o4; o4.x = y0; o4.y = y1; o4.z = y2; o4.w = y3;
        ((float4*)of32)[(size_t)row * (D_/4) + tid] = o4;
    }
}

// ======================================================================
// Pipelined MFMA GEMMs: double-buffered LDS + prefetch-next-tile,
// ONE __syncthreads per K-step (drain lands after compute -> latency hidden).
// global_load_lds(16B) staging, linear LDS layout. 4 waves / 256 threads.
// ======================================================================

// ---------------- dual GEMM 128x64: A[M,K]bf16 @ {B1t,B2t}[N,K]bf16, gated epilogue
// MODE 0: phi = elu(silu(p1+b1)*(p2+b2))+1 -> f32
// MODE 1: g   = silu(p1+b1)*(p2+b2)        -> f32
template<int MODE>
__global__ __launch_bounds__(256) void gemm_dual128(const bf16* __restrict__ A,
                                                    const bf16* __restrict__ B1,
                                                    const bf16* __restrict__ B2,
                                                    const float* __restrict__ bias1,
                                                    const float* __restrict__ bias2,
                                                    float* __restrict__ out,
                                                    int N, int K) {
    __shared__ alignas(16) bf16 As [2][128 * 32];
    __shared__ alignas(16) bf16 B1s[2][64 * 32];
    __shared__ alignas(16) bf16 B2s[2][64 * 32];
    const int tid = threadIdx.x;
    const int wave = tid >> 6, lane = tid & 63;
    const int nb = blockIdx.x, mb = blockIdx.y;
    const int wr = (wave >> 1) * 64;
    const int wc = (wave & 1) * 32;
    const int fr = lane & 15, fk = (lane >> 4) * 8;
    const int srow = lane >> 2, scol = (lane & 3) * 8;
    const int co = wave * 512;
    const bf16* Ap0 = A  + (size_t)(mb * 128 + wave * 16 + srow) * K + scol;
    const bf16* Ap1 = A  + (size_t)(mb * 128 + (wave + 4) * 16 + srow) * K + scol;
    const bf16* B1p = B1 + (size_t)(nb * 64 + wave * 16 + srow) * K + scol;
    const bf16* B2p = B2 + (size_t)(nb * 64 + wave * 16 + srow) * K + scol;
    f32x4 acc1[4][2] = {};
    f32x4 acc2[4][2] = {};
    // prologue: stage tile 0
    gl16(Ap0, &As[0][co]);
    gl16(Ap1, &As[0][co + 2048]);
    gl16(B1p, &B1s[0][co]);
    gl16(B2p, &B2s[0][co]);
    __syncthreads();
    int cur = 0;
    for (int k0 = 32; k0 < K; k0 += 32) {
        int nxt = cur ^ 1;
        gl16(Ap0 + k0, &As[nxt][co]);
        gl16(Ap1 + k0, &As[nxt][co + 2048]);
        gl16(B1p + k0, &B1s[nxt][co]);
        gl16(B2p + k0, &B2s[nxt][co]);
        bf16x8 af[4];
        #pragma unroll
        for (int mi = 0; mi < 4; mi++)
            af[mi] = *(const bf16x8*)&As[cur][(wr + mi * 16 + fr) * 32 + fk];
        #pragma unroll
        for (int ni = 0; ni < 2; ni++) {
            bf16x8 b1f = *(const bf16x8*)&B1s[cur][(wc + ni * 16 + fr) * 32 + fk];
            bf16x8 b2f = *(const bf16x8*)&B2s[cur][(wc + ni * 16 + fr) * 32 + fk];
            #pragma unroll
            for (int mi = 0; mi < 4; mi++) {
                acc1[mi][ni] = __builtin_amdgcn_mfma_f32_16x16x32_bf16(af[mi], b1f, acc1[mi][ni], 0, 0, 0);
                acc2[mi][ni] = __builtin_amdgcn_mfma_f32_16x16x32_bf16(af[mi], b2f, acc2[mi][ni], 0, 0, 0);
            }
        }
        __syncthreads();   // drains vmcnt(0): nxt staged; all waves done reading cur
        cur = nxt;
    }
    {   // last tile
        bf16x8 af[4];
        #pragma unroll
        for (int mi = 0; mi < 4; mi++)
            af[mi] = *(const bf16x8*)&As[cur][(wr + mi * 16 + fr) * 32 + fk];
        #pragma unroll
        for (int ni = 0; ni < 2; ni++) {
            bf16x8 b1f = *(const bf16x8*)&B1s[cur][(wc + ni * 16 + fr) * 32 + fk];
            bf16x8 b2f = *(const bf16x8*)&B2s[cur][(wc + ni * 16 + fr) * 32 + fk];
            #pragma unroll
            for (int mi = 0; mi < 4; mi++) {
                acc1[mi][ni] = __builtin_amdgcn_mfma_f32_16x16x32_bf16(af[mi], b1f, acc1[mi][ni], 0, 0, 0);
                acc2[mi][ni] = __builtin_amdgcn_mfma_f32_16x16x32_bf16(af[mi], b2f, acc2[mi][ni], 0, 0, 0);
            }
        }
    }
    const int col = lane & 15, rowq = (lane >> 4) * 4;
    #pragma unroll
    for (int ni = 0; ni < 2; ni++) {
        int gn = nb * 64 + wc + ni * 16 + col;
        float bb1 = bias1[gn], bb2 = bias2[gn];
        #pragma unroll
        for (int mi = 0; mi < 4; mi++) {
            #pragma unroll
            for (int r = 0; r < 4; r++) {
                int gm = mb * 128 + wr + mi * 16 + rowq + r;
                float p1 = acc1[mi][ni][r] + bb1;
                float p2 = acc2[mi][ni][r] + bb2;
                float g = (p1 / (1.0f + expf(-p1))) * p2;   // silu(p1)*p2
                size_t idx = (size_t)gm * N + gn;
                if (MODE == 0) {
                    float e = g > 0.0f ? g : expm1f(g);
                    out[idx] = e + 1.0f;
                } else {
                    out[idx] = g;
                }
            }
        }
    }
}

// ---------------- single GEMM 128x128 (wo): A[M,K]bf16 @ Bt[N,K]bf16 -> f32
__global__ __launch_bounds__(256) void gemm_single128(const bf16* __restrict__ A,
                                                      const bf16* __restrict__ Bt,
                                                      float* __restrict__ out,
                                                      int N, int K) {
    __shared__ alignas(16) bf16 As[2][128 * 32];
    __shared__ alignas(16) bf16 Bs[2][128 * 32];
    const int tid = threadIdx.x;
    const int wave = tid >> 6, lane = tid & 63;
    const int nb = blockIdx.x, mb = blockIdx.y;
    const int wr = (wave >> 1) * 64, wc = (wave & 1) * 64;
    const int fr = lane & 15, fk = (lane >> 4) * 8;
    const int srow = lane >> 2, scol = (lane & 3) * 8;
    const int co = wave * 512;
    const bf16* Ap0 = A  + (size_t)(mb * 128 + wave * 16 + srow) * K + scol;
    const bf16* Ap1 = A  + (size_t)(mb * 128 + (wave + 4) * 16 + srow) * K + scol;
    const bf16* Bp0 = Bt + (size_t)(nb * 128 + wave * 16 + srow) * K + scol;
    const bf16* Bp1 = Bt + (size_t)(nb * 128 + (wave + 4) * 16 + srow) * K + scol;
    f32x4 acc[4][4] = {};
    gl16(Ap0, &As[0][co]);
    gl16(Ap1, &As[0][co + 2048]);
    gl16(Bp0, &Bs[0][co]);
    gl16(Bp1, &Bs[0][co + 2048]);
    __syncthreads();
    int cur = 0;
    for (int k0 = 32; k0 < K; k0 += 32) {
        int nxt = cur ^ 1;
        gl16(Ap0 + k0, &As[nxt][co]);
        gl16(Ap1 + k0, &As[nxt][co + 2048]);
        gl16(Bp0 + k0, &Bs[nxt][co]);
        gl16(Bp1 + k0, &Bs[nxt][co + 2048]);
        bf16x8 af[4], bf[4];
        #pragma unroll
        for (int mi = 0; mi < 4; mi++)
            af[mi] = *(const bf16x8*)&As[cur][(wr + mi * 16 + fr) * 32 + fk];
        #pragma unroll
        for (int ni = 0; ni < 4; ni++)
            bf[ni] = *(const bf16x8*)&Bs[cur][(wc + ni * 16 + fr) * 32 + fk];
        #pragma unroll
        for (int ni = 0; ni < 4; ni++)
            #pragma unroll
            for (int mi = 0; mi < 4; mi++)
                acc[mi][ni] = __builtin_amdgcn_mfma_f32_16x16x32_bf16(af[mi], bf[ni], acc[mi][ni], 0, 0, 0);
        __syncthreads();
        cur = nxt;
    }
    {
        bf16x8 af[4], bf[4];
        #pragma unroll
        for (int mi = 0; mi < 4; mi++)
            af[mi] = *(const bf16x8*)&As[cur][(wr + mi * 16 + fr) * 32 + fk];
        #pragma unroll
        for (int ni = 0; ni < 4; ni++)
            bf[ni] = *(const bf16x8*)&Bs[cur][(wc + ni * 16 + fr) * 32 + fk];
        #pragma unroll
        for (int ni = 0; ni < 4; ni++)
            #pragma unroll
            for (int mi = 0; mi < 4; mi++)
                acc[mi][ni] = __builtin_amdgcn_mfma_f32_16x16x32_bf16(af[mi], bf[ni], acc[mi][ni], 0, 0, 0);
    }
    const int col = lane & 15, rowq = (lane >> 4) * 4;
    #pragma unroll
    for (int ni = 0; ni < 4; ni++) {
        int gn = nb * 128 + wc + ni * 16 + col;
        #pragma unroll
        for (int mi = 0; mi < 4; mi++)
            #pragma unroll
            for (int r = 0; r < 4; r++) {
                int gm = mb * 128 + wr + mi * 16 + rowq + r;
                out[(size_t)gm * N + gn] = acc[mi][ni][r];
            }
    }
}

// ---------------- MoE up-proj 128x64, ALL experts batched (z=expert), gathered rows
__global__ __launch_bounds__(256) void gemm_dual_moe128(const bf16* __restrict__ A,
                                                        const bf16* __restrict__ B1all,
                                                        const bf16* __restrict__ B2all,
                                                        const float* __restrict__ b1all,
                                                        const float* __restrict__ b2all,
                                                        const int* __restrict__ list,
                                                        const int* __restrict__ counts,
                                                        const int* __restrict__ ebase,
                                                        bf16* __restrict__ outAct,
                                                        int N, int K) {
    const int e = blockIdx.z;
    const int cnt = counts[e * 64];
    const int mb = blockIdx.y;
    if (mb * 128 >= cnt) return;
    __shared__ alignas(16) bf16 As [2][128 * 32];
    __shared__ alignas(16) bf16 B1s[2][64 * 32];
    __shared__ alignas(16) bf16 B2s[2][64 * 32];
    const bf16* B1 = B1all + (size_t)e * N * K;
    const bf16* B2 = B2all + (size_t)e * N * K;
    const float* bias1 = b1all + (size_t)e * N;
    const float* bias2 = b2all + (size_t)e * N;
    const int tid = threadIdx.x;
    const int wave = tid >> 6, lane = tid & 63;
    const int nb = blockIdx.x;
    const int wr = (wave >> 1) * 64, wc = (wave & 1) * 32;
    const int fr = lane & 15, fk = (lane >> 4) * 8;
    const int srow = lane >> 2, scol = (lane & 3) * 8;
    const int co = wave * 512;
    int gr0 = mb * 128 + wave * 16 + srow;
    int gr1 = mb * 128 + (wave + 4) * 16 + srow;
    int tok0 = list[e * T_ + (gr0 < cnt ? gr0 : cnt - 1)];
    int tok1 = list[e * T_ + (gr1 < cnt ? gr1 : cnt - 1)];
    const bf16* Ap0 = A  + (size_t)tok0 * K + scol;
    const bf16* Ap1 = A  + (size_t)tok1 * K + scol;
    const bf16* B1p = B1 + (size_t)(nb * 64 + wave * 16 + srow) * K + scol;
    const bf16* B2p = B2 + (size_t)(nb * 64 + wave * 16 + srow) * K + scol;
    f32x4 acc1[4][2] = {};
    f32x4 acc2[4][2] = {};
    gl16(Ap0, &As[0][co]);
    gl16(Ap1, &As[0][co + 2048]);
    gl16(B1p, &B1s[0][co]);
    gl16(B2p, &B2s[0][co]);
    __syncthreads();
    int cur = 0;
    for (int k0 = 32; k0 < K; k0 += 32) {
        int nxt = cur ^ 1;
        gl16(Ap0 + k0, &As[nxt][co]);
        gl16(Ap1 + k0, &As[nxt][co + 2048]);
        gl16(B1p + k0, &B1s[nxt][co]);
        gl16(B2p + k0, &B2s[nxt][co]);
        bf16x8 af[4];
        #pragma unroll
        for (int mi = 0; mi < 4; mi++)
            af[mi] = *(const bf16x8*)&As[cur][(wr + mi * 16 + fr) * 32 + fk];
        #pragma unroll
        for (int ni = 0; ni < 2; ni++) {
            bf16x8 b1f = *(const bf16x8*)&B1s[cur][(wc + ni * 16 + fr) * 32 + fk];
            bf16x8 b2f = *(const bf16x8*)&B2s[cur][(wc + ni * 16 + fr) * 32 + fk];
            #pragma unroll
            for (int mi = 0; mi < 4; mi++) {
                acc1[mi][ni] = __builtin_amdgcn_mfma_f32_16x16x32_bf16(af[mi], b1f, acc1[mi][ni], 0, 0, 0);
                acc2[mi][ni] = __builtin_amdgcn_mfma_f32_16x16x32_bf16(af[mi], b2f, acc2[mi][ni], 0, 0, 0);
            }
        }
        __syncthreads();
        cur = nxt;
    }
    {
        bf16x8 af[4];
        #pragma unroll
        for (int mi = 0; mi < 4; mi++)
            af[mi] = *(const bf16x8*)&As[cur][(wr + mi * 16 + fr) * 32 + fk];
        #pragma unroll
        for (int ni = 0; ni < 2; ni++) {
            bf16x8 b1f = *(const bf16x8*)&B1s[cur][(wc + ni * 16 + fr) * 32 + fk];
            bf16x8 b2f = *(const bf16x8*)&B2s[cur][(wc + ni * 16 + fr) * 32 + fk];
            #pragma unroll
            for (int mi = 0; mi < 4; mi++) {
                acc1[mi][ni] = __builtin_amdgcn_mfma_f32_16x16x32_bf16(af[mi], b1f, acc1[mi][ni], 0, 0, 0);
                acc2[mi][ni] = __builtin_amdgcn_mfma_f32_16x16x32_bf16(af[mi], b2f, acc2[mi][ni], 0, 0, 0);
            }
        }
    }
    const int col = lane & 15, rowq = (lane >> 4) * 4;
    const size_t rbase = (size_t)ebase[e] + mb * 128;
    #pragma unroll
    for (int ni = 0; ni < 2; ni++) {
        int gn = nb * 64 + wc + ni * 16 + col;
        float bb1 = bias1[gn], bb2 = bias2[gn];
        #pragma unroll
        for (int mi = 0; mi < 4; mi++)
            #pragma unroll
            for (int r = 0; r < 4; r++) {
                int lm = wr + mi * 16 + rowq + r;
                float p1 = acc1[mi][ni][r] + bb1;
                float p2 = acc2[mi][ni][r] + bb2;
                float g = (p1 / (1.0f + expf(-p1))) * p2;
                outAct[(rbase + lm) * N + gn] = (bf16)g;
            }
    }
}

// ---------------- MoE down-proj 128x128, ALL experts batched: atomicAdd scatter
__global__ __launch_bounds__(256) void gemm_down_moe128(const bf16* __restrict__ Act,
                                                        const bf16* __restrict__ Ball,
                                                        const float* __restrict__ ball,
                                                        const int* __restrict__ list,
                                                        const float* __restrict__ wgt,
                                                        const int* __restrict__ counts,
                                                        const int* __restrict__ ebase,
                                                        float* __restrict__ out,
                                                        int N, int K) {
    const int e = blockIdx.z;
    const int cnt = counts[e * 64];
    const int mb = blockIdx.y;
    if (mb * 128 >= cnt) return;
    __shared__ alignas(16) bf16 As[2][128 * 32];
    __shared__ alignas(16) bf16 Bs[2][128 * 32];
    const bf16* A  = Act + (size_t)ebase[e] * K;
    const bf16* Bt = Ball + (size_t)e * N * K;
    const float* bias = ball + (size_t)e * N;
    const int tid = threadIdx.x;
    const int wave = tid >> 6, lane = tid & 63;
    const int nb = blockIdx.x;
    const int wr = (wave >> 1) * 64, wc = (wave & 1) * 64;
    const int fr = lane & 15, fk = (lane >> 4) * 8;
    const int srow = lane >> 2, scol = (lane & 3) * 8;
    const int co = wave * 512;
    const bf16* Ap0 = A  + (size_t)(mb * 128 + wave * 16 + srow) * K + scol;
    const bf16* Ap1 = A  + (size_t)(mb * 128 + (wave + 4) * 16 + srow) * K + scol;
    const bf16* Bp0 = Bt + (size_t)(nb * 128 + wave * 16 + srow) * K + scol;
    const bf16* Bp1 = Bt + (size_t)(nb * 128 + (wave + 4) * 16 + srow) * K + scol;
    f32x4 acc[4][4] = {};
    gl16(Ap0, &As[0][co]);
    gl16(Ap1, &As[0][co + 2048]);
    gl16(Bp0, &Bs[0][co]);
    gl16(Bp1, &Bs[0][co + 2048]);
    __syncthreads();
    int cur = 0;
    for (int k0 = 32; k0 < K; k0 += 32) {
        int nxt = cur ^ 1;
        gl16(Ap0 + k0, &As[nxt][co]);
        gl16(Ap1 + k0, &As[nxt][co + 2048]);
        gl16(Bp0 + k0, &Bs[nxt][co]);
        gl16(Bp1 + k0, &Bs[nxt][co + 2048]);
        bf16x8 af[4], bf[4];
        #pragma unroll
        for (int mi = 0; mi < 4; mi++)
            af[mi] = *(const bf16x8*)&As[cur][(wr + mi * 16 + fr) * 32 + fk];
        #pragma unroll
        for (int ni = 0; ni < 4; ni++)
            bf[ni] = *(const bf16x8*)&Bs[cur][(wc + ni * 16 + fr) * 32 + fk];
        #pragma unroll
        for (int ni = 0; ni < 4; ni++)
            #pragma unroll
            for (int mi = 0; mi < 4; mi++)
                acc[mi][ni] = __builtin_amdgcn_mfma_f32_16x16x32_bf16(af[mi], bf[ni], acc[mi][ni], 0, 0, 0);
        __syncthreads();
        cur = nxt;
    }
    {
        bf16x8 af[4], bf[4];
        #pragma unroll
        for (int mi = 0; mi < 4; mi++)
            af[mi] = *(const bf16x8*)&As[cur][(wr + mi * 16 + fr) * 32 + fk];
        #pragma unroll
        for (int ni = 0; ni < 4; ni++)
            bf[ni] = *(const bf16x8*)&Bs[cur][(wc + ni * 16 + fr) * 32 + fk];
        #pragma unroll
        for (int ni = 0; ni < 4; ni++)
            #pragma unroll
            for (int mi = 0; mi < 4; mi++)
                acc[mi][ni] = __builtin_amdgcn_mfma_f32_16x16x32_bf16(af[mi], bf[ni], acc[mi][ni], 0, 0, 0);
    }
    const int col = lane & 15, rowq = (lane >> 4) * 4;
    #pragma unroll
    for (int ni = 0; ni < 4; ni++) {
        int gn = nb * 128 + wc + ni * 16 + col;
        float bb = bias[gn];
        #pragma unroll
        for (int mi = 0; mi < 4; mi++)
            #pragma unroll
            for (int r = 0; r < 4; r++) {
                int gm = mb * 128 + wr + mi * 16 + rowq + r;
                if (gm < cnt) {
                    int tok = list[e * T_ + gm];
                    float w = wgt[e * T_ + gm];
                    atomicAdd(&out[(size_t)tok * N + gn], (acc[mi][ni][r] + bb) * w);
                }
            }
    }
}

// ---------------- linear attention partials: chunk c covers s in [c*256, (c+1)*256)
__global__ __launch_bounds__(256) void attn_kv_part(const float* __restrict__ phi_k,
                                                    const float* __restrict__ vv_g,
                                                    float* __restrict__ kvp,
                                                    float* __restrict__ ksp) {
    int bh = blockIdx.x;      // 32
    int chunk = blockIdx.y;   // 8
    int b = bh >> 4, h = bh & 15;
    __shared__ float pk[64][68];
    __shared__ float vv[64][68];
    int tid = threadIdx.x;
    int d0 = (tid >> 4) * 4;
    int e0 = (tid & 15) * 4;
    float acc[4][4] = {};
    float ks[4] = {};
    int sbeg = chunk * (S_ / 8);
    for (int s0 = sbeg; s0 < sbeg + S_ / 8; s0 += 64) {
        __syncthreads();
        for (int i = tid; i < 1024; i += 256) {
            int r = i >> 4, c4 = i & 15;
            size_t base = ((size_t)(b * S_ + s0 + r) * D_ + h * 64);
            ((float4*)&pk[r][0])[c4] = ((const float4*)(phi_k + base))[c4];
            ((float4*)&vv[r][0])[c4] = ((const float4*)(vv_g + base))[c4];
        }
        __syncthreads();
        for (int s = 0; s < 64; s++) {
            float a0 = pk[s][d0], a1 = pk[s][d0+1], a2 = pk[s][d0+2], a3 = pk[s][d0+3];
            float b0 = vv[s][e0], b1 = vv[s][e0+1], b2 = vv[s][e0+2], b3 = vv[s][e0+3];
            acc[0][0] += a0*b0; acc[0][1] += a0*b1; acc[0][2] += a0*b2; acc[0][3] += a0*b3;
            acc[1][0] += a1*b0; acc[1][1] += a1*b1; acc[1][2] += a1*b2; acc[1][3] += a1*b3;
            acc[2][0] += a2*b0; acc[2][1] += a2*b1; acc[2][2] += a2*b2; acc[2][3] += a2*b3;
            acc[3][0] += a3*b0; acc[3][1] += a3*b1; acc[3][2] += a3*b2; acc[3][3] += a3*b3;
            if ((tid & 15) == 0) { ks[0] += a0; ks[1] += a1; ks[2] += a2; ks[3] += a3; }
        }
    }
    float* kvo = kvp + ((size_t)bh * 8 + chunk) * 4096;
    for (int i = 0; i < 4; i++)
        for (int j = 0; j < 4; j++)
            kvo[(d0 + i) * 64 + e0 + j] = acc[i][j];
    if ((tid & 15) == 0)
        for (int i = 0; i < 4; i++) ksp[((size_t)bh * 8 + chunk) * 64 + d0 + i] = ks[i];
}

__global__ __launch_bounds__(256) void attn_kv_reduce(const float* __restrict__ kvp,
                                                      const float* __restrict__ ksp,
                                                      float* __restrict__ kv,
                                                      float* __restrict__ ksum) {
    int bh = blockIdx.x;
    int tid = threadIdx.x;
    #pragma unroll
    for (int i = 0; i < 4; i++) {
        int idx = i * 256 + tid;
        float4 s = {0, 0, 0, 0};
        #pragma unroll
        for (int c = 0; c < 8; c++) {
            float4 p = ((const float4*)(kvp + ((size_t)bh * 8 + c) * 4096))[idx];
            s.x += p.x; s.y += p.y; s.z += p.z; s.w += p.w;
        }
        ((float4*)(kv + (size_t)bh * 4096))[idx] = s;
    }
    if (tid < 64) {
        float s = 0;
        #pragma unroll
        for (int c = 0; c < 8; c++) s += ksp[((size_t)bh * 8 + c) * 64 + tid];
        ksum[bh * 64 + tid] = s;
    }
}

// ---------------- attn numerator
__global__ __launch_bounds__(256) void attn_num(const float* __restrict__ phi_q,
                                                const float* __restrict__ kv,
                                                const float* __restrict__ ksum,
                                                bf16* __restrict__ outb) {
    int bh = blockIdx.y;
    int b = bh >> 4, h = bh & 15;
    int s0 = blockIdx.x * 64;
    __shared__ float kvs[64][64];
    __shared__ float pqs[64][68];
    __shared__ float kss[64];
    int tid = threadIdx.x;
    const float* kvsrc = kv + (size_t)bh * 4096;
    for (int i = tid; i < 1024; i += 256) ((float4*)kvs)[i] = ((const float4*)kvsrc)[i];
    if (tid < 16) ((float4*)kss)[tid] = ((const float4*)(ksum + bh * 64))[tid];
    for (int i = tid; i < 1024; i += 256) {
        int r = i >> 4, c4 = i & 15;
        ((float4*)&pqs[r][0])[c4] =
            ((const float4*)(phi_q + ((size_t)(b * S_ + s0 + r) * D_ + h * 64)))[c4];
    }
    __syncthreads();
    int tok = tid >> 2;
    int e0  = (tid & 3) * 16;
    float acc[16] = {};
    float qk = 0.0f;
    for (int d = 0; d < 64; d++) {
        float pq = pqs[tok][d];
        qk += pq * kss[d];
        #pragma unroll
        for (int ei = 0; ei < 16; ei++) acc[ei] += pq * kvs[d][e0 + ei];
    }
    float inv = 1.0f / (qk + 1e-6f);
    int t = b * S_ + s0 + tok;
    bf16* op = outb + (size_t)t * D_ + h * 64 + e0;
    #pragma unroll
    for (int ei = 0; ei < 16; ei++) op[ei] = (bf16)(acc[ei] * inv);
}

// ---------------- residual: x1 = x + wo_prod + bo ; also seed d_out with x1
__global__ __launch_bounds__(256) void residual_kernel(const float* __restrict__ x,
                                                       const float* __restrict__ prod,
                                                       const float* __restrict__ bo,
                                                       float* __restrict__ x1,
                                                       float* __restrict__ outp) {
    int i = blockIdx.x * 256 + threadIdx.x;       // float4 index
    float4 xv = ((const float4*)x)[i];
    float4 pv = ((const float4*)prod)[i];
    float4 bv = ((const float4*)bo)[i & 255];
    float4 r;
    r.x = xv.x + pv.x + bv.x; r.y = xv.y + pv.y + bv.y;
    r.z = xv.z + pv.z + bv.z; r.w = xv.w + pv.w + bv.w;
    ((float4*)x1)[i] = r;
    ((float4*)outp)[i] = r;
}

// ---------------- zero the per-expert counters (padded: stride 64 ints = 256B / line)
__global__ void zero_counts(int* counts) {
    counts[threadIdx.x] = 0;   // launched with 512 threads
}

// ---------------- prefix bases for compacted Act rows (counts padded to 128 rows)
__global__ void expert_bases(const int* __restrict__ counts, int* __restrict__ ebase) {
    if (threadIdx.x == 0) {
        int b = 0;
        #pragma unroll
        for (int e = 0; e < E_; e++) {
            ebase[e] = b;
            b += (counts[e * 64] + 127) & ~127;
        }
    }
}

// ---------------- gate: softmax top-2, normalized weights; assign token to expert lists
// counts[] strided 64 ints apart so the 8 experts' atomics hit 8 different L2 lines
__global__ __launch_bounds__(256) void gate_kernel(const float* __restrict__ x2f,
                                                   const float* __restrict__ gw,
                                                   const float* __restrict__ gb,
                                                   int* __restrict__ counts,
                                                   int* __restrict__ list,
                                                   float* __restrict__ wgt) {
    int tid = threadIdx.x;
    int wave = tid >> 6, lane = tid & 63;
    int t = blockIdx.x * 4 + wave;
    const float* xr = x2f + (size_t)t * D_;
    float le[8] = {};
    for (int i = 0; i < 16; i++) {
        int d = lane + i * 64;
        float xv = xr[d];
        const float4* g4 = (const float4*)(gw + (size_t)d * 8);
        float4 a = g4[0], b = g4[1];
        le[0] += xv * a.x; le[1] += xv * a.y; le[2] += xv * a.z; le[3] += xv * a.w;
        le[4] += xv * b.x; le[5] += xv * b.y; le[6] += xv * b.z; le[7] += xv * b.w;
    }
    #pragma unroll
    for (int o = 1; o < 64; o <<= 1)
        #pragma unroll
        for (int e = 0; e < 8; e++) le[e] += __shfl_xor(le[e], o);
    if (lane == 0) {
        float probs[8]; float mx = -1e30f;
        for (int e = 0; e < 8; e++) { le[e] += gb[e]; mx = fmaxf(mx, le[e]); }
        float s = 0.0f;
        for (int e = 0; e < 8; e++) { probs[e] = expf(le[e] - mx); s += probs[e]; }
        float invs = 1.0f / s;
        for (int e = 0; e < 8; e++) probs[e] *= invs;
        int i1 = 0; float v1 = probs[0];
        for (int e = 1; e < 8; e++) if (probs[e] > v1) { v1 = probs[e]; i1 = e; }
        int i2 = -1; float v2 = -1.0f;
        for (int e = 0; e < 8; e++) if (e != i1 && probs[e] > v2) { v2 = probs[e]; i2 = e; }
        float inv = 1.0f / (v1 + v2 + 1e-6f);
        int p1 = atomicAdd(&counts[i1 * 64], 1);
        list[i1 * T_ + p1] = t; wgt[i1 * T_ + p1] = v1 * inv;
        int p2 = atomicAdd(&counts[i2 * 64], 1);
        list[i2 * T_ + p2] = t; wgt[i2 * T_ + p2] = v2 * inv;
    }
}

extern "C" void kernel_launch(void* const* d_in, const int* in_sizes, int n_in,
                              void* d_out, int out_size, void* d_ws, size_t ws_size,
                              hipStream_t stream) {
    const float* x    = (const float*)d_in[0];
    const float* wq1  = (const float*)d_in[1];
    const float* bq1  = (const float*)d_in[2];
    const float* wq2  = (const float*)d_in[3];
    const float* bq2  = (const float*)d_in[4];
    const float* wk1  = (const float*)d_in[5];
    const float* bk1  = (const float*)d_in[6];
    const float* wk2  = (const float*)d_in[7];
    const float* bk2  = (const float*)d_in[8];
    const float* wv1  = (const float*)d_in[9];
    const float* bv1  = (const float*)d_in[10];
    const float* wv2  = (const float*)d_in[11];
    const float* bv2  = (const float*)d_in[12];
    const float* wo   = (const float*)d_in[13];
    const float* bo   = (const float*)d_in[14];
    const float* ln1g = (const float*)d_in[15];
    const float* ln1b = (const float*)d_in[16];
    const float* ln2g = (const float*)d_in[17];
    const float* ln2b = (const float*)d_in[18];
    const float* gw   = (const float*)d_in[19];
    const float* gb   = (const float*)d_in[20];
    const float* ew1  = (const float*)d_in[21];
    const float* eb1  = (const float*)d_in[22];
    const float* ew2  = (const float*)d_in[23];
    const float* eb2  = (const float*)d_in[24];
    const float* ew3  = (const float*)d_in[25];
    const float* eb3  = (const float*)d_in[26];
    float* out = (float*)d_out;

    char* wsb = (char*)d_ws;
    size_t off = 0;
    auto carve = [&](size_t bytes) -> char* {
        char* r = wsb + off;
        off = (off + bytes + 255) & ~(size_t)255;
        return r;
    };
    bf16* Wq1t = (bf16*)carve((size_t)D_ * D_ * 2);
    bf16* Wq2t = (bf16*)carve((size_t)D_ * D_ * 2);
    bf16* Wk1t = (bf16*)carve((size_t)D_ * D_ * 2);
    bf16* Wk2t = (bf16*)carve((size_t)D_ * D_ * 2);
    bf16* Wv1t = (bf16*)carve((size_t)D_ * D_ * 2);
    bf16* Wv2t = (bf16*)carve((size_t)D_ * D_ * 2);
    bf16* Wot  = (bf16*)carve((size_t)D_ * D_ * 2);
    bf16* We1t = (bf16*)carve((size_t)E_ * D_ * F_ * 2);
    bf16* We3t = (bf16*)carve((size_t)E_ * D_ * F_ * 2);
    bf16* We2t = (bf16*)carve((size_t)E_ * D_ * F_ * 2);
    bf16*  X2b  = (bf16*)carve((size_t)T_ * D_ * 2);
    float* PhiQ = (float*)carve((size_t)T_ * D_ * 4);   // } Act (bf16, <=75.5MB) aliases
    float* PhiK = (float*)carve((size_t)T_ * D_ * 4);   // } PhiQ..WoP (80.3MB span, all
    float* Vb   = (float*)carve((size_t)T_ * D_ * 4);   // } dead before MoE up-proj)
    float* KV   = (float*)carve((size_t)B_ * H_ * 64 * 64 * 4);
    float* KS   = (float*)carve((size_t)B_ * H_ * 64 * 4);
    float* KVp  = (float*)carve((size_t)B_ * H_ * 8 * 64 * 64 * 4);
    float* KSp  = (float*)carve((size_t)B_ * H_ * 8 * 64 * 4);
    bf16*  Attn = (bf16*)carve((size_t)T_ * D_ * 2);
    float* WoP  = (float*)carve((size_t)T_ * D_ * 4);   // X2f aliases WoP
    float* X1   = (float*)carve((size_t)T_ * D_ * 4);
    bf16*  X2c  = (bf16*)carve((size_t)T_ * D_ * 2);
    int*   Cnt  = (int*)carve((size_t)E_ * 64 * 4);     // padded: one line per expert
    int*   List = (int*)carve((size_t)E_ * T_ * 4);
    float* Wgt  = (float*)carve((size_t)E_ * T_ * 4);
    int*   Ebase = (int*)carve((size_t)E_ * 4);
    bf16*  Act  = (bf16*)PhiQ;   // compacted expert rows: <= 9208 x F_ bf16 = 75.5MB
    float* X2f  = WoP;           // dead after gate

    dim3 tb32(32, 8);
    // weight transposes -> bf16 [N][K]
    transpose_convert<<<dim3(32, 32, 1), tb32, 0, stream>>>(wq1, Wq1t, D_, D_);
    transpose_convert<<<dim3(32, 32, 1), tb32, 0, stream>>>(wq2, Wq2t, D_, D_);
    transpose_convert<<<dim3(32, 32, 1), tb32, 0, stream>>>(wk1, Wk1t, D_, D_);
    transpose_convert<<<dim3(32, 32, 1), tb32, 0, stream>>>(wk2, Wk2t, D_, D_);
    transpose_convert<<<dim3(32, 32, 1), tb32, 0, stream>>>(wv1, Wv1t, D_, D_);
    transpose_convert<<<dim3(32, 32, 1), tb32, 0, stream>>>(wv2, Wv2t, D_, D_);
    transpose_convert<<<dim3(32, 32, 1), tb32, 0, stream>>>(wo,  Wot,  D_, D_);
    transpose_convert<<<dim3(F_/32, D_/32, E_), tb32, 0, stream>>>(ew1, We1t, D_, F_);
    transpose_convert<<<dim3(F_/32, D_/32, E_), tb32, 0, stream>>>(ew3, We3t, D_, F_);
    transpose_convert<<<dim3(D_/32, F_/32, E_), tb32, 0, stream>>>(ew2, We2t, F_, D_);

    zero_counts<<<1, E_ * 64, 0, stream>>>(Cnt);

    // LN1 -> bf16
    ln_kernel<<<T_, 256, 0, stream>>>(x, ln1g, ln1b, X2b, nullptr);

    // QKV gated projections (fused phi for q,k) -- pipelined 128x64 GEMMs
    gemm_dual128<0><<<dim3(D_/64, T_/128), 256, 0, stream>>>(X2b, Wq1t, Wq2t, bq1, bq2, PhiQ, D_, D_);
    gemm_dual128<0><<<dim3(D_/64, T_/128), 256, 0, stream>>>(X2b, Wk1t, Wk2t, bk1, bk2, PhiK, D_, D_);
    gemm_dual128<1><<<dim3(D_/64, T_/128), 256, 0, stream>>>(X2b, Wv1t, Wv2t, bv1, bv2, Vb,   D_, D_);

    // linear attention (chunked partials + reduce)
    attn_kv_part<<<dim3(B_ * H_, 8), 256, 0, stream>>>(PhiK, Vb, KVp, KSp);
    attn_kv_reduce<<<B_ * H_, 256, 0, stream>>>(KVp, KSp, KV, KS);
    attn_num<<<dim3(S_/64, B_ * H_), 256, 0, stream>>>(PhiQ, KV, KS, Attn);

    // output projection + residual
    gemm_single128<<<dim3(D_/128, T_/128), 256, 0, stream>>>(Attn, Wot, WoP, D_, D_);
    residual_kernel<<<T_ * D_ / 1024, 256, 0, stream>>>(x, WoP, bo, X1, out);

    // LN2 (bf16 for GEMMs, fp32 for gate), gate + expert assignment
    ln_kernel<<<T_, 256, 0, stream>>>(X1, ln2g, ln2b, X2c, X2f);
    gate_kernel<<<T_ / 4, 256, 0, stream>>>(X2f, gw, gb, Cnt, List, Wgt);
    expert_bases<<<1, 64, 0, stream>>>(Cnt, Ebase);

    // sparse MoE: all experts batched via blockIdx.z; up-proj gathers rows into
    // compacted Act, down-proj (128x128) scatter-adds (atomic) into d_out
    gemm_dual_moe128<<<dim3(F_/64, T_/128, E_), 256, 0, stream>>>(
        X2c, We1t, We3t, eb1, eb3, List, Cnt, Ebase, Act, F_, D_);
    gemm_down_moe128<<<dim3(D_/128, T_/128, E_), 256, 0, stream>>>(
        Act, We2t, eb2, List, Wgt, Cnt, Ebase, out, D_, F_);
}

// Round 3
// 1125.465 us; speedup vs baseline: 1.0299x; 1.0299x over previous
//
#include <hip/hip_runtime.h>
#include <cstdint>
#include <cstddef>

typedef __bf16 bf16;
typedef bf16  bf16x8 __attribute__((ext_vector_type(8)));
typedef bf16  bf16x4 __attribute__((ext_vector_type(4)));
typedef float f32x4  __attribute__((ext_vector_type(4)));

#define B_ 2
#define S_ 2048
#define D_ 1024
#define H_ 16
#define F_ 4096
#define E_ 8
#define T_ (B_*S_)   // 4096 tokens

// ---------------- async global->LDS, 16B per lane (dest = wave-uniform base + lane*16)
__device__ __forceinline__ void gl16(const bf16* g, bf16* l) {
    __builtin_amdgcn_global_load_lds(
        (const __attribute__((address_space(1))) void*)g,
        (__attribute__((address_space(3))) void*)l, 16, 0, 0);
}

// ---------------- transpose + fp32->bf16 convert:  in [R][C] f32  ->  out [C][R] bf16
// 64(C) x 256(R) tiles; coalesced float4 loads, transpose-on-LDS-write with XOR
// row swizzle (key from c>>2 so stride-4-c lanes spread 8 banks), bf16x8 row writes.
__global__ __launch_bounds__(256) void transpose_convert(const float* __restrict__ in,
                                                         bf16* __restrict__ out,
                                                         int R, int C) {
    __shared__ bf16 tbuf[64 * 256];   // [c][r^key(c)]
    size_t mat = blockIdx.z;
    in  += mat * (size_t)R * C;
    out += mat * (size_t)R * C;
    int c0 = blockIdx.x * 64, r0 = blockIdx.y * 256;
    for (int i = threadIdx.x; i < 256 * 16; i += 256) {
        int row = i >> 4, cb = (i & 15) * 4;
        float4 v = *(const float4*)(in + (size_t)(r0 + row) * C + c0 + cb);
        float vv[4] = {v.x, v.y, v.z, v.w};
        #pragma unroll
        for (int k = 0; k < 4; k++) {
            int c = cb + k;
            int key = ((c >> 2) & 7) << 3;
            tbuf[c * 256 + (row ^ key)] = (bf16)vv[k];
        }
    }
    __syncthreads();
    for (int i = threadIdx.x; i < 64 * 32; i += 256) {
        int c = i >> 5, r8 = (i & 31) * 8;
        int key = ((c >> 2) & 7) << 3;
        *(bf16x8*)(out + (size_t)(c0 + c) * R + r0 + r8) =
            *(const bf16x8*)&tbuf[c * 256 + (r8 ^ key)];
    }
}

// ---------------- LayerNorm (eps=1e-5): writes bf16 (GEMM input) and optional fp32
__global__ __launch_bounds__(256) void ln_kernel(const float* __restrict__ xin,
                                                 const float* __restrict__ gam,
                                                 const float* __restrict__ bet,
                                                 bf16* __restrict__ obf,
                                                 float* __restrict__ of32) {
    int row = blockIdx.x, tid = threadIdx.x;
    const float4* xr = (const float4*)(xin + (size_t)row * D_);
    float4 v = xr[tid];
    float s  = v.x + v.y + v.z + v.w;
    float s2 = v.x*v.x + v.y*v.y + v.z*v.z + v.w*v.w;
    #pragma unroll
    for (int o = 1; o < 64; o <<= 1) { s += __shfl_xor(s, o); s2 += __shfl_xor(s2, o); }
    __shared__ float red[8];
    int wave = tid >> 6, lane = tid & 63;
    if (lane == 0) { red[wave] = s; red[4 + wave] = s2; }
    __syncthreads();
    s  = red[0] + red[1] + red[2] + red[3];
    s2 = red[4] + red[5] + red[6] + red[7];
    float m   = s * (1.0f / D_);
    float var = s2 * (1.0f / D_) - m * m;
    float rs  = rsqrtf(var + 1e-5f);
    float4 gv = ((const float4*)gam)[tid];
    float4 bv = ((const float4*)bet)[tid];
    float y0 = (v.x - m) * rs * gv.x + bv.x;
    float y1 = (v.y - m) * rs * gv.y + bv.y;
    float y2 = (v.z - m) * rs * gv.z + bv.z;
    float y3 = (v.w - m) * rs * gv.w + bv.w;
    bf16x4 ov; ov[0] = (bf16)y0; ov[1] = (bf16)y1; ov[2] = (bf16)y2; ov[3] = (bf16)y3;
    *(bf16x4*)(obf + (size_t)row * D_ + tid * 4) = ov;
    if (of32) {
        float4 o4; o4.x = y0; o4.y = y1; o4.z = y2; o4.w = y3;
        ((float4*)of32)[(size_t)row * (D_/4) + tid] = o4;
    }
}

// ======================================================================
// Counted-vmcnt pipelined MFMA GEMMs (T4-lite): 3-slot LDS rotation,
// depth-2 prefetch via global_load_lds, raw s_barrier + asm vmcnt(4)
// (never drain to 0 in the main loop). One barrier per K-step; every
// buffer handoff is barrier-protected. BK=32, 48KB LDS, 4 waves.
// ======================================================================

// ---------------- dual GEMM 128x64: A[M,K]bf16 @ {B1t,B2t}[N,K]bf16, gated epilogue
// MODE 0: phi = elu(silu(p1+b1)*(p2+b2))+1 -> f32
// MODE 1: g   = silu(p1+b1)*(p2+b2)        -> f32
template<int MODE>
__global__ __launch_bounds__(256) void gemm_dual128(const bf16* __restrict__ A,
                                                    const bf16* __restrict__ B1,
                                                    const bf16* __restrict__ B2,
                                                    const float* __restrict__ bias1,
                                                    const float* __restrict__ bias2,
                                                    float* __restrict__ out,
                                                    int N, int K) {
    __shared__ alignas(16) bf16 As [3][128 * 32];
    __shared__ alignas(16) bf16 B1s[3][64 * 32];
    __shared__ alignas(16) bf16 B2s[3][64 * 32];
    const int tid = threadIdx.x;
    const int wave = tid >> 6, lane = tid & 63;
    const int nb = blockIdx.x, mb = blockIdx.y;
    const int wr = (wave >> 1) * 64, wc = (wave & 1) * 32;
    const int fr = lane & 15, fk = (lane >> 4) * 8;
    const int srow = lane >> 2, scol = (lane & 3) * 8;
    const int co = wave * 512;
    const bf16* Ap0 = A  + (size_t)(mb * 128 + wave * 16 + srow) * K + scol;
    const bf16* Ap1 = A  + (size_t)(mb * 128 + (wave + 4) * 16 + srow) * K + scol;
    const bf16* B1p = B1 + (size_t)(nb * 64 + wave * 16 + srow) * K + scol;
    const bf16* B2p = B2 + (size_t)(nb * 64 + wave * 16 + srow) * K + scol;
    f32x4 acc1[4][2] = {};
    f32x4 acc2[4][2] = {};
    const int NT = K >> 5;
#define STG_DU(t_, s_) { int k0_ = (t_) << 5; \
        gl16(Ap0 + k0_, &As[s_][co]); \
        gl16(Ap1 + k0_, &As[s_][co + 2048]); \
        gl16(B1p + k0_, &B1s[s_][co]); \
        gl16(B2p + k0_, &B2s[s_][co]); }
    STG_DU(0, 0); STG_DU(1, 1);
    asm volatile("s_waitcnt vmcnt(4)" ::: "memory");
    __builtin_amdgcn_s_barrier();
    for (int t = 0; t < NT; ++t) {
        int s = t % 3;
        if (t + 2 < NT) STG_DU(t + 2, (t + 2) % 3);
        bf16x8 af[4];
        #pragma unroll
        for (int mi = 0; mi < 4; mi++)
            af[mi] = *(const bf16x8*)&As[s][(wr + mi * 16 + fr) * 32 + fk];
        #pragma unroll
        for (int ni = 0; ni < 2; ni++) {
            bf16x8 b1f = *(const bf16x8*)&B1s[s][(wc + ni * 16 + fr) * 32 + fk];
            bf16x8 b2f = *(const bf16x8*)&B2s[s][(wc + ni * 16 + fr) * 32 + fk];
            #pragma unroll
            for (int mi = 0; mi < 4; mi++) {
                acc1[mi][ni] = __builtin_amdgcn_mfma_f32_16x16x32_bf16(af[mi], b1f, acc1[mi][ni], 0, 0, 0);
                acc2[mi][ni] = __builtin_amdgcn_mfma_f32_16x16x32_bf16(af[mi], b2f, acc2[mi][ni], 0, 0, 0);
            }
        }
        if (t + 1 < NT) {
            if (t + 2 < NT) asm volatile("s_waitcnt vmcnt(4) lgkmcnt(0)" ::: "memory");
            else            asm volatile("s_waitcnt vmcnt(0) lgkmcnt(0)" ::: "memory");
            __builtin_amdgcn_s_barrier();
        }
    }
#undef STG_DU
    const int col = lane & 15, rowq = (lane >> 4) * 4;
    #pragma unroll
    for (int ni = 0; ni < 2; ni++) {
        int gn = nb * 64 + wc + ni * 16 + col;
        float bb1 = bias1[gn], bb2 = bias2[gn];
        #pragma unroll
        for (int mi = 0; mi < 4; mi++) {
            #pragma unroll
            for (int r = 0; r < 4; r++) {
                int gm = mb * 128 + wr + mi * 16 + rowq + r;
                float p1 = acc1[mi][ni][r] + bb1;
                float p2 = acc2[mi][ni][r] + bb2;
                float g = (p1 / (1.0f + expf(-p1))) * p2;   // silu(p1)*p2
                size_t idx = (size_t)gm * N + gn;
                if (MODE == 0) {
                    float e = g > 0.0f ? g : expm1f(g);
                    out[idx] = e + 1.0f;
                } else {
                    out[idx] = g;
                }
            }
        }
    }
}

// ---------------- single GEMM 128x128 (wo): A[M,K]bf16 @ Bt[N,K]bf16 -> f32
__global__ __launch_bounds__(256) void gemm_single128(const bf16* __restrict__ A,
                                                      const bf16* __restrict__ Bt,
                                                      float* __restrict__ out,
                                                      int N, int K) {
    __shared__ alignas(16) bf16 As[3][128 * 32];
    __shared__ alignas(16) bf16 Bs[3][128 * 32];
    const int tid = threadIdx.x;
    const int wave = tid >> 6, lane = tid & 63;
    const int nb = blockIdx.x, mb = blockIdx.y;
    const int wr = (wave >> 1) * 64, wc = (wave & 1) * 64;
    const int fr = lane & 15, fk = (lane >> 4) * 8;
    const int srow = lane >> 2, scol = (lane & 3) * 8;
    const int co = wave * 512;
    const bf16* Ap0 = A  + (size_t)(mb * 128 + wave * 16 + srow) * K + scol;
    const bf16* Ap1 = A  + (size_t)(mb * 128 + (wave + 4) * 16 + srow) * K + scol;
    const bf16* Bp0 = Bt + (size_t)(nb * 128 + wave * 16 + srow) * K + scol;
    const bf16* Bp1 = Bt + (size_t)(nb * 128 + (wave + 4) * 16 + srow) * K + scol;
    f32x4 acc[4][4] = {};
    const int NT = K >> 5;
#define STG_SG(t_, s_) { int k0_ = (t_) << 5; \
        gl16(Ap0 + k0_, &As[s_][co]); \
        gl16(Ap1 + k0_, &As[s_][co + 2048]); \
        gl16(Bp0 + k0_, &Bs[s_][co]); \
        gl16(Bp1 + k0_, &Bs[s_][co + 2048]); }
    STG_SG(0, 0); STG_SG(1, 1);
    asm volatile("s_waitcnt vmcnt(4)" ::: "memory");
    __builtin_amdgcn_s_barrier();
    for (int t = 0; t < NT; ++t) {
        int s = t % 3;
        if (t + 2 < NT) STG_SG(t + 2, (t + 2) % 3);
        bf16x8 af[4], bf[4];
        #pragma unroll
        for (int mi = 0; mi < 4; mi++)
            af[mi] = *(const bf16x8*)&As[s][(wr + mi * 16 + fr) * 32 + fk];
        #pragma unroll
        for (int ni = 0; ni < 4; ni++)
            bf[ni] = *(const bf16x8*)&Bs[s][(wc + ni * 16 + fr) * 32 + fk];
        #pragma unroll
        for (int ni = 0; ni < 4; ni++)
            #pragma unroll
            for (int mi = 0; mi < 4; mi++)
                acc[mi][ni] = __builtin_amdgcn_mfma_f32_16x16x32_bf16(af[mi], bf[ni], acc[mi][ni], 0, 0, 0);
        if (t + 1 < NT) {
            if (t + 2 < NT) asm volatile("s_waitcnt vmcnt(4) lgkmcnt(0)" ::: "memory");
            else            asm volatile("s_waitcnt vmcnt(0) lgkmcnt(0)" ::: "memory");
            __builtin_amdgcn_s_barrier();
        }
    }
#undef STG_SG
    const int col = lane & 15, rowq = (lane >> 4) * 4;
    #pragma unroll
    for (int ni = 0; ni < 4; ni++) {
        int gn = nb * 128 + wc + ni * 16 + col;
        #pragma unroll
        for (int mi = 0; mi < 4; mi++)
            #pragma unroll
            for (int r = 0; r < 4; r++) {
                int gm = mb * 128 + wr + mi * 16 + rowq + r;
                out[(size_t)gm * N + gn] = acc[mi][ni][r];
            }
    }
}

// ---------------- MoE up-proj 128x64, ALL experts batched (z=expert), gathered rows
__global__ __launch_bounds__(256) void gemm_dual_moe128(const bf16* __restrict__ A,
                                                        const bf16* __restrict__ B1all,
                                                        const bf16* __restrict__ B2all,
                                                        const float* __restrict__ b1all,
                                                        const float* __restrict__ b2all,
                                                        const int* __restrict__ list,
                                                        const int* __restrict__ counts,
                                                        const int* __restrict__ ebase,
                                                        bf16* __restrict__ outAct,
                                                        int N, int K) {
    const int e = blockIdx.z;
    const int cnt = counts[e * 64];
    const int mb = blockIdx.y;
    if (mb * 128 >= cnt) return;
    __shared__ alignas(16) bf16 As [3][128 * 32];
    __shared__ alignas(16) bf16 B1s[3][64 * 32];
    __shared__ alignas(16) bf16 B2s[3][64 * 32];
    const bf16* B1 = B1all + (size_t)e * N * K;
    const bf16* B2 = B2all + (size_t)e * N * K;
    const float* bias1 = b1all + (size_t)e * N;
    const float* bias2 = b2all + (size_t)e * N;
    const int tid = threadIdx.x;
    const int wave = tid >> 6, lane = tid & 63;
    const int nb = blockIdx.x;
    const int wr = (wave >> 1) * 64, wc = (wave & 1) * 32;
    const int fr = lane & 15, fk = (lane >> 4) * 8;
    const int srow = lane >> 2, scol = (lane & 3) * 8;
    const int co = wave * 512;
    int gr0 = mb * 128 + wave * 16 + srow;
    int gr1 = mb * 128 + (wave + 4) * 16 + srow;
    int tok0 = list[e * T_ + (gr0 < cnt ? gr0 : cnt - 1)];
    int tok1 = list[e * T_ + (gr1 < cnt ? gr1 : cnt - 1)];
    const bf16* Ap0 = A  + (size_t)tok0 * K + scol;
    const bf16* Ap1 = A  + (size_t)tok1 * K + scol;
    const bf16* B1p = B1 + (size_t)(nb * 64 + wave * 16 + srow) * K + scol;
    const bf16* B2p = B2 + (size_t)(nb * 64 + wave * 16 + srow) * K + scol;
    f32x4 acc1[4][2] = {};
    f32x4 acc2[4][2] = {};
    const int NT = K >> 5;
#define STG_MU(t_, s_) { int k0_ = (t_) << 5; \
        gl16(Ap0 + k0_, &As[s_][co]); \
        gl16(Ap1 + k0_, &As[s_][co + 2048]); \
        gl16(B1p + k0_, &B1s[s_][co]); \
        gl16(B2p + k0_, &B2s[s_][co]); }
    STG_MU(0, 0); STG_MU(1, 1);
    asm volatile("s_waitcnt vmcnt(4)" ::: "memory");
    __builtin_amdgcn_s_barrier();
    for (int t = 0; t < NT; ++t) {
        int s = t % 3;
        if (t + 2 < NT) STG_MU(t + 2, (t + 2) % 3);
        bf16x8 af[4];
        #pragma unroll
        for (int mi = 0; mi < 4; mi++)
            af[mi] = *(const bf16x8*)&As[s][(wr + mi * 16 + fr) * 32 + fk];
        #pragma unroll
        for (int ni = 0; ni < 2; ni++) {
            bf16x8 b1f = *(const bf16x8*)&B1s[s][(wc + ni * 16 + fr) * 32 + fk];
            bf16x8 b2f = *(const bf16x8*)&B2s[s][(wc + ni * 16 + fr) * 32 + fk];
            #pragma unroll
            for (int mi = 0; mi < 4; mi++) {
                acc1[mi][ni] = __builtin_amdgcn_mfma_f32_16x16x32_bf16(af[mi], b1f, acc1[mi][ni], 0, 0, 0);
                acc2[mi][ni] = __builtin_amdgcn_mfma_f32_16x16x32_bf16(af[mi], b2f, acc2[mi][ni], 0, 0, 0);
            }
        }
        if (t + 1 < NT) {
            if (t + 2 < NT) asm volatile("s_waitcnt vmcnt(4) lgkmcnt(0)" ::: "memory");
            else            asm volatile("s_waitcnt vmcnt(0) lgkmcnt(0)" ::: "memory");
            __builtin_amdgcn_s_barrier();
        }
    }
#undef STG_MU
    const int col = lane & 15, rowq = (lane >> 4) * 4;
    const size_t rbase = (size_t)ebase[e] + mb * 128;
    #pragma unroll
    for (int ni = 0; ni < 2; ni++) {
        int gn = nb * 64 + wc + ni * 16 + col;
        float bb1 = bias1[gn], bb2 = bias2[gn];
        #pragma unroll
        for (int mi = 0; mi < 4; mi++)
            #pragma unroll
            for (int r = 0; r < 4; r++) {
                int lm = wr + mi * 16 + rowq + r;
                float p1 = acc1[mi][ni][r] + bb1;
                float p2 = acc2[mi][ni][r] + bb2;
                float g = (p1 / (1.0f + expf(-p1))) * p2;
                outAct[(rbase + lm) * N + gn] = (bf16)g;
            }
    }
}

// ---------------- MoE down-proj 128x128, ALL experts batched: atomicAdd scatter
__global__ __launch_bounds__(256) void gemm_down_moe128(const bf16* __restrict__ Act,
                                                        const bf16* __restrict__ Ball,
                                                        const float* __restrict__ ball,
                                                        const int* __restrict__ list,
                                                        const float* __restrict__ wgt,
                                                        const int* __restrict__ counts,
                                                        const int* __restrict__ ebase,
                                                        float* __restrict__ out,
                                                        int N, int K) {
    const int e = blockIdx.z;
    const int cnt = counts[e * 64];
    const int mb = blockIdx.y;
    if (mb * 128 >= cnt) return;
    __shared__ alignas(16) bf16 As[3][128 * 32];
    __shared__ alignas(16) bf16 Bs[3][128 * 32];
    const bf16* A  = Act + (size_t)ebase[e] * K;
    const bf16* Bt = Ball + (size_t)e * N * K;
    const float* bias = ball + (size_t)e * N;
    const int tid = threadIdx.x;
    const int wave = tid >> 6, lane = tid & 63;
    const int nb = blockIdx.x;
    const int wr = (wave >> 1) * 64, wc = (wave & 1) * 64;
    const int fr = lane & 15, fk = (lane >> 4) * 8;
    const int srow = lane >> 2, scol = (lane & 3) * 8;
    const int co = wave * 512;
    const bf16* Ap0 = A  + (size_t)(mb * 128 + wave * 16 + srow) * K + scol;
    const bf16* Ap1 = A  + (size_t)(mb * 128 + (wave + 4) * 16 + srow) * K + scol;
    const bf16* Bp0 = Bt + (size_t)(nb * 128 + wave * 16 + srow) * K + scol;
    const bf16* Bp1 = Bt + (size_t)(nb * 128 + (wave + 4) * 16 + srow) * K + scol;
    f32x4 acc[4][4] = {};
    const int NT = K >> 5;
#define STG_MD(t_, s_) { int k0_ = (t_) << 5; \
        gl16(Ap0 + k0_, &As[s_][co]); \
        gl16(Ap1 + k0_, &As[s_][co + 2048]); \
        gl16(Bp0 + k0_, &Bs[s_][co]); \
        gl16(Bp1 + k0_, &Bs[s_][co + 2048]); }
    STG_MD(0, 0); STG_MD(1, 1);
    asm volatile("s_waitcnt vmcnt(4)" ::: "memory");
    __builtin_amdgcn_s_barrier();
    for (int t = 0; t < NT; ++t) {
        int s = t % 3;
        if (t + 2 < NT) STG_MD(t + 2, (t + 2) % 3);
        bf16x8 af[4], bf[4];
        #pragma unroll
        for (int mi = 0; mi < 4; mi++)
            af[mi] = *(const bf16x8*)&As[s][(wr + mi * 16 + fr) * 32 + fk];
        #pragma unroll
        for (int ni = 0; ni < 4; ni++)
            bf[ni] = *(const bf16x8*)&Bs[s][(wc + ni * 16 + fr) * 32 + fk];
        #pragma unroll
        for (int ni = 0; ni < 4; ni++)
            #pragma unroll
            for (int mi = 0; mi < 4; mi++)
                acc[mi][ni] = __builtin_amdgcn_mfma_f32_16x16x32_bf16(af[mi], bf[ni], acc[mi][ni], 0, 0, 0);
        if (t + 1 < NT) {
            if (t + 2 < NT) asm volatile("s_waitcnt vmcnt(4) lgkmcnt(0)" ::: "memory");
            else            asm volatile("s_waitcnt vmcnt(0) lgkmcnt(0)" ::: "memory");
            __builtin_amdgcn_s_barrier();
        }
    }
#undef STG_MD
    const int col = lane & 15, rowq = (lane >> 4) * 4;
    #pragma unroll
    for (int ni = 0; ni < 4; ni++) {
        int gn = nb * 128 + wc + ni * 16 + col;
        float bb = bias[gn];
        #pragma unroll
        for (int mi = 0; mi < 4; mi++)
            #pragma unroll
            for (int r = 0; r < 4; r++) {
                int gm = mb * 128 + wr + mi * 16 + rowq + r;
                if (gm < cnt) {
                    int tok = list[e * T_ + gm];
                    float w = wgt[e * T_ + gm];
                    atomicAdd(&out[(size_t)tok * N + gn], (acc[mi][ni][r] + bb) * w);
                }
            }
    }
}

// ---------------- linear attention partials: chunk c covers s in [c*256, (c+1)*256)
__global__ __launch_bounds__(256) void attn_kv_part(const float* __restrict__ phi_k,
                                                    const float* __restrict__ vv_g,
                                                    float* __restrict__ kvp,
                                                    float* __restrict__ ksp) {
    int bh = blockIdx.x;      // 32
    int chunk = blockIdx.y;   // 8
    int b = bh >> 4, h = bh & 15;
    __shared__ float pk[64][68];
    __shared__ float vv[64][68];
    int tid = threadIdx.x;
    int d0 = (tid >> 4) * 4;
    int e0 = (tid & 15) * 4;
    float acc[4][4] = {};
    float ks[4] = {};
    int sbeg = chunk * (S_ / 8);
    for (int s0 = sbeg; s0 < sbeg + S_ / 8; s0 += 64) {
        __syncthreads();
        for (int i = tid; i < 1024; i += 256) {
            int r = i >> 4, c4 = i & 15;
            size_t base = ((size_t)(b * S_ + s0 + r) * D_ + h * 64);
            ((float4*)&pk[r][0])[c4] = ((const float4*)(phi_k + base))[c4];
            ((float4*)&vv[r][0])[c4] = ((const float4*)(vv_g + base))[c4];
        }
        __syncthreads();
        for (int s = 0; s < 64; s++) {
            float a0 = pk[s][d0], a1 = pk[s][d0+1], a2 = pk[s][d0+2], a3 = pk[s][d0+3];
            float b0 = vv[s][e0], b1 = vv[s][e0+1], b2 = vv[s][e0+2], b3 = vv[s][e0+3];
            acc[0][0] += a0*b0; acc[0][1] += a0*b1; acc[0][2] += a0*b2; acc[0][3] += a0*b3;
            acc[1][0] += a1*b0; acc[1][1] += a1*b1; acc[1][2] += a1*b2; acc[1][3] += a1*b3;
            acc[2][0] += a2*b0; acc[2][1] += a2*b1; acc[2][2] += a2*b2; acc[2][3] += a2*b3;
            acc[3][0] += a3*b0; acc[3][1] += a3*b1; acc[3][2] += a3*b2; acc[3][3] += a3*b3;
            if ((tid & 15) == 0) { ks[0] += a0; ks[1] += a1; ks[2] += a2; ks[3] += a3; }
        }
    }
    float* kvo = kvp + ((size_t)bh * 8 + chunk) * 4096;
    for (int i = 0; i < 4; i++)
        for (int j = 0; j < 4; j++)
            kvo[(d0 + i) * 64 + e0 + j] = acc[i][j];
    if ((tid & 15) == 0)
        for (int i = 0; i < 4; i++) ksp[((size_t)bh * 8 + chunk) * 64 + d0 + i] = ks[i];
}

__global__ __launch_bounds__(256) void attn_kv_reduce(const float* __restrict__ kvp,
                                                      const float* __restrict__ ksp,
                                                      float* __restrict__ kv,
                                                      float* __restrict__ ksum) {
    int bh = blockIdx.x;
    int tid = threadIdx.x;
    #pragma unroll
    for (int i = 0; i < 4; i++) {
        int idx = i * 256 + tid;
        float4 s = {0, 0, 0, 0};
        #pragma unroll
        for (int c = 0; c < 8; c++) {
            float4 p = ((const float4*)(kvp + ((size_t)bh * 8 + c) * 4096))[idx];
            s.x += p.x; s.y += p.y; s.z += p.z; s.w += p.w;
        }
        ((float4*)(kv + (size_t)bh * 4096))[idx] = s;
    }
    if (tid < 64) {
        float s = 0;
        #pragma unroll
        for (int c = 0; c < 8; c++) s += ksp[((size_t)bh * 8 + c) * 64 + tid];
        ksum[bh * 64 + tid] = s;
    }
}

// ---------------- attn numerator
__global__ __launch_bounds__(256) void attn_num(const float* __restrict__ phi_q,
                                                const float* __restrict__ kv,
                                                const float* __restrict__ ksum,
                                                bf16* __restrict__ outb) {
    int bh = blockIdx.y;
    int b = bh >> 4, h = bh & 15;
    int s0 = blockIdx.x * 64;
    __shared__ float kvs[64][64];
    __shared__ float pqs[64][68];
    __shared__ float kss[64];
    int tid = threadIdx.x;
    const float* kvsrc = kv + (size_t)bh * 4096;
    for (int i = tid; i < 1024; i += 256) ((float4*)kvs)[i] = ((const float4*)kvsrc)[i];
    if (tid < 16) ((float4*)kss)[tid] = ((const float4*)(ksum + bh * 64))[tid];
    for (int i = tid; i < 1024; i += 256) {
        int r = i >> 4, c4 = i & 15;
        ((float4*)&pqs[r][0])[c4] =
            ((const float4*)(phi_q + ((size_t)(b * S_ + s0 + r) * D_ + h * 64)))[c4];
    }
    __syncthreads();
    int tok = tid >> 2;
    int e0  = (tid & 3) * 16;
    float acc[16] = {};
    float qk = 0.0f;
    for (int d = 0; d < 64; d++) {
        float pq = pqs[tok][d];
        qk += pq * kss[d];
        #pragma unroll
        for (int ei = 0; ei < 16; ei++) acc[ei] += pq * kvs[d][e0 + ei];
    }
    float inv = 1.0f / (qk + 1e-6f);
    int t = b * S_ + s0 + tok;
    bf16* op = outb + (size_t)t * D_ + h * 64 + e0;
    #pragma unroll
    for (int ei = 0; ei < 16; ei++) op[ei] = (bf16)(acc[ei] * inv);
}

// ---------------- residual: x1 = x + wo_prod + bo ; also seed d_out with x1
__global__ __launch_bounds__(256) void residual_kernel(const float* __restrict__ x,
                                                       const float* __restrict__ prod,
                                                       const float* __restrict__ bo,
                                                       float* __restrict__ x1,
                                                       float* __restrict__ outp) {
    int i = blockIdx.x * 256 + threadIdx.x;       // float4 index
    float4 xv = ((const float4*)x)[i];
    float4 pv = ((const float4*)prod)[i];
    float4 bv = ((const float4*)bo)[i & 255];
    float4 r;
    r.x = xv.x + pv.x + bv.x; r.y = xv.y + pv.y + bv.y;
    r.z = xv.z + pv.z + bv.z; r.w = xv.w + pv.w + bv.w;
    ((float4*)x1)[i] = r;
    ((float4*)outp)[i] = r;
}

// ---------------- zero the per-expert counters (padded: stride 64 ints = 256B / line)
__global__ void zero_counts(int* counts) {
    counts[threadIdx.x] = 0;   // launched with 512 threads
}

// ---------------- prefix bases for compacted Act rows (counts padded to 128 rows)
__global__ void expert_bases(const int* __restrict__ counts, int* __restrict__ ebase) {
    if (threadIdx.x == 0) {
        int b = 0;
        #pragma unroll
        for (int e = 0; e < E_; e++) {
            ebase[e] = b;
            b += (counts[e * 64] + 127) & ~127;
        }
    }
}

// ---------------- gate: softmax top-2, normalized weights; assign token to expert lists
// counts[] strided 64 ints apart so the 8 experts' atomics hit 8 different L2 lines
__global__ __launch_bounds__(256) void gate_kernel(const float* __restrict__ x2f,
                                                   const float* __restrict__ gw,
                                                   const float* __restrict__ gb,
                                                   int* __restrict__ counts,
                                                   int* __restrict__ list,
                                                   float* __restrict__ wgt) {
    int tid = threadIdx.x;
    int wave = tid >> 6, lane = tid & 63;
    int t = blockIdx.x * 4 + wave;
    const float* xr = x2f + (size_t)t * D_;
    float le[8] = {};
    for (int i = 0; i < 16; i++) {
        int d = lane + i * 64;
        float xv = xr[d];
        const float4* g4 = (const float4*)(gw + (size_t)d * 8);
        float4 a = g4[0], b = g4[1];
        le[0] += xv * a.x; le[1] += xv * a.y; le[2] += xv * a.z; le[3] += xv * a.w;
        le[4] += xv * b.x; le[5] += xv * b.y; le[6] += xv * b.z; le[7] += xv * b.w;
    }
    #pragma unroll
    for (int o = 1; o < 64; o <<= 1)
        #pragma unroll
        for (int e = 0; e < 8; e++) le[e] += __shfl_xor(le[e], o);
    if (lane == 0) {
        float probs[8]; float mx = -1e30f;
        for (int e = 0; e < 8; e++) { le[e] += gb[e]; mx = fmaxf(mx, le[e]); }
        float s = 0.0f;
        for (int e = 0; e < 8; e++) { probs[e] = expf(le[e] - mx); s += probs[e]; }
        float invs = 1.0f / s;
        for (int e = 0; e < 8; e++) probs[e] *= invs;
        int i1 = 0; float v1 = probs[0];
        for (int e = 1; e < 8; e++) if (probs[e] > v1) { v1 = probs[e]; i1 = e; }
        int i2 = -1; float v2 = -1.0f;
        for (int e = 0; e < 8; e++) if (e != i1 && probs[e] > v2) { v2 = probs[e]; i2 = e; }
        float inv = 1.0f / (v1 + v2 + 1e-6f);
        int p1 = atomicAdd(&counts[i1 * 64], 1);
        list[i1 * T_ + p1] = t; wgt[i1 * T_ + p1] = v1 * inv;
        int p2 = atomicAdd(&counts[i2 * 64], 1);
        list[i2 * T_ + p2] = t; wgt[i2 * T_ + p2] = v2 * inv;
    }
}

extern "C" void kernel_launch(void* const* d_in, const int* in_sizes, int n_in,
                              void* d_out, int out_size, void* d_ws, size_t ws_size,
                              hipStream_t stream) {
    const float* x    = (const float*)d_in[0];
    const float* wq1  = (const float*)d_in[1];
    const float* bq1  = (const float*)d_in[2];
    const float* wq2  = (const float*)d_in[3];
    const float* bq2  = (const float*)d_in[4];
    const float* wk1  = (const float*)d_in[5];
    const float* bk1  = (const float*)d_in[6];
    const float* wk2  = (const float*)d_in[7];
    const float* bk2  = (const float*)d_in[8];
    const float* wv1  = (const float*)d_in[9];
    const float* bv1  = (const float*)d_in[10];
    const float* wv2  = (const float*)d_in[11];
    const float* bv2  = (const float*)d_in[12];
    const float* wo   = (const float*)d_in[13];
    const float* bo   = (const float*)d_in[14];
    const float* ln1g = (const float*)d_in[15];
    const float* ln1b = (const float*)d_in[16];
    const float* ln2g = (const float*)d_in[17];
    const float* ln2b = (const float*)d_in[18];
    const float* gw   = (const float*)d_in[19];
    const float* gb   = (const float*)d_in[20];
    const float* ew1  = (const float*)d_in[21];
    const float* eb1  = (const float*)d_in[22];
    const float* ew2  = (const float*)d_in[23];
    const float* eb2  = (const float*)d_in[24];
    const float* ew3  = (const float*)d_in[25];
    const float* eb3  = (const float*)d_in[26];
    float* out = (float*)d_out;

    char* wsb = (char*)d_ws;
    size_t off = 0;
    auto carve = [&](size_t bytes) -> char* {
        char* r = wsb + off;
        off = (off + bytes + 255) & ~(size_t)255;
        return r;
    };
    bf16* Wq1t = (bf16*)carve((size_t)D_ * D_ * 2);
    bf16* Wq2t = (bf16*)carve((size_t)D_ * D_ * 2);
    bf16* Wk1t = (bf16*)carve((size_t)D_ * D_ * 2);
    bf16* Wk2t = (bf16*)carve((size_t)D_ * D_ * 2);
    bf16* Wv1t = (bf16*)carve((size_t)D_ * D_ * 2);
    bf16* Wv2t = (bf16*)carve((size_t)D_ * D_ * 2);
    bf16* Wot  = (bf16*)carve((size_t)D_ * D_ * 2);
    bf16* We1t = (bf16*)carve((size_t)E_ * D_ * F_ * 2);
    bf16* We3t = (bf16*)carve((size_t)E_ * D_ * F_ * 2);
    bf16* We2t = (bf16*)carve((size_t)E_ * D_ * F_ * 2);
    bf16*  X2b  = (bf16*)carve((size_t)T_ * D_ * 2);
    float* PhiQ = (float*)carve((size_t)T_ * D_ * 4);   // } Act (bf16, <=75.5MB) aliases
    float* PhiK = (float*)carve((size_t)T_ * D_ * 4);   // } PhiQ..WoP (dead before MoE)
    float* Vb   = (float*)carve((size_t)T_ * D_ * 4);
    float* KV   = (float*)carve((size_t)B_ * H_ * 64 * 64 * 4);
    float* KS   = (float*)carve((size_t)B_ * H_ * 64 * 4);
    float* KVp  = (float*)carve((size_t)B_ * H_ * 8 * 64 * 64 * 4);
    float* KSp  = (float*)carve((size_t)B_ * H_ * 8 * 64 * 4);
    bf16*  Attn = (bf16*)carve((size_t)T_ * D_ * 2);
    float* WoP  = (float*)carve((size_t)T_ * D_ * 4);   // X2f aliases WoP
    float* X1   = (float*)carve((size_t)T_ * D_ * 4);
    bf16*  X2c  = (bf16*)carve((size_t)T_ * D_ * 2);
    int*   Cnt  = (int*)carve((size_t)E_ * 64 * 4);     // padded: one line per expert
    int*   List = (int*)carve((size_t)E_ * T_ * 4);
    float* Wgt  = (float*)carve((size_t)E_ * T_ * 4);
    int*   Ebase = (int*)carve((size_t)E_ * 4);
    bf16*  Act  = (bf16*)PhiQ;   // compacted expert rows: <= 9208 x F_ bf16 = 75.5MB
    float* X2f  = WoP;           // dead after gate

    // weight transposes -> bf16 [N][K]   (64-col x 256-row tiles)
    transpose_convert<<<dim3(D_/64, D_/256, 1), 256, 0, stream>>>(wq1, Wq1t, D_, D_);
    transpose_convert<<<dim3(D_/64, D_/256, 1), 256, 0, stream>>>(wq2, Wq2t, D_, D_);
    transpose_convert<<<dim3(D_/64, D_/256, 1), 256, 0, stream>>>(wk1, Wk1t, D_, D_);
    transpose_convert<<<dim3(D_/64, D_/256, 1), 256, 0, stream>>>(wk2, Wk2t, D_, D_);
    transpose_convert<<<dim3(D_/64, D_/256, 1), 256, 0, stream>>>(wv1, Wv1t, D_, D_);
    transpose_convert<<<dim3(D_/64, D_/256, 1), 256, 0, stream>>>(wv2, Wv2t, D_, D_);
    transpose_convert<<<dim3(D_/64, D_/256, 1), 256, 0, stream>>>(wo,  Wot,  D_, D_);
    transpose_convert<<<dim3(F_/64, D_/256, E_), 256, 0, stream>>>(ew1, We1t, D_, F_);
    transpose_convert<<<dim3(F_/64, D_/256, E_), 256, 0, stream>>>(ew3, We3t, D_, F_);
    transpose_convert<<<dim3(D_/64, F_/256, E_), 256, 0, stream>>>(ew2, We2t, F_, D_);

    zero_counts<<<1, E_ * 64, 0, stream>>>(Cnt);

    // LN1 -> bf16
    ln_kernel<<<T_, 256, 0, stream>>>(x, ln1g, ln1b, X2b, nullptr);

    // QKV gated projections (fused phi for q,k) -- counted-vmcnt pipelined GEMMs
    gemm_dual128<0><<<dim3(D_/64, T_/128), 256, 0, stream>>>(X2b, Wq1t, Wq2t, bq1, bq2, PhiQ, D_, D_);
    gemm_dual128<0><<<dim3(D_/64, T_/128), 256, 0, stream>>>(X2b, Wk1t, Wk2t, bk1, bk2, PhiK, D_, D_);
    gemm_dual128<1><<<dim3(D_/64, T_/128), 256, 0, stream>>>(X2b, Wv1t, Wv2t, bv1, bv2, Vb,   D_, D_);

    // linear attention (chunked partials + reduce)
    attn_kv_part<<<dim3(B_ * H_, 8), 256, 0, stream>>>(PhiK, Vb, KVp, KSp);
    attn_kv_reduce<<<B_ * H_, 256, 0, stream>>>(KVp, KSp, KV, KS);
    attn_num<<<dim3(S_/64, B_ * H_), 256, 0, stream>>>(PhiQ, KV, KS, Attn);

    // output projection + residual
    gemm_single128<<<dim3(D_/128, T_/128), 256, 0, stream>>>(Attn, Wot, WoP, D_, D_);
    residual_kernel<<<T_ * D_ / 1024, 256, 0, stream>>>(x, WoP, bo, X1, out);

    // LN2 (bf16 for GEMMs, fp32 for gate), gate + expert assignment
    ln_kernel<<<T_, 256, 0, stream>>>(X1, ln2g, ln2b, X2c, X2f);
    gate_kernel<<<T_ / 4, 256, 0, stream>>>(X2f, gw, gb, Cnt, List, Wgt);
    expert_bases<<<1, 64, 0, stream>>>(Cnt, Ebase);

    // sparse MoE: all experts batched via blockIdx.z; up-proj gathers rows into
    // compacted Act, down-proj (128x128) scatter-adds (atomic) into d_out
    gemm_dual_moe128<<<dim3(F_/64, T_/128, E_), 256, 0, stream>>>(
        X2c, We1t, We3t, eb1, eb3, List, Cnt, Ebase, Act, F_, D_);
    gemm_down_moe128<<<dim3(D_/128, T_/128, E_), 256, 0, stream>>>(
        Act, We2t, eb2, List, Wgt, Cnt, Ebase, out, D_, F_);
}